// Round 1
// baseline (499.467 us; speedup 1.0000x reference)
//
#include <hip/hip_runtime.h>
#include <cmath>

// Problem constants (from reference)
#define C_DIM 8000
#define N_TOTAL 10500
#define B_DIM 256

__device__ __forceinline__ void merge_softmax_argmax(float& m, float& s, int& idx,
                                                     float m2, float s2, int i2) {
    if (m2 > m) {
        // new max from the other side
        s = s * expf(m - m2) + s2;   // expf(-inf - finite) = 0 handles empty side
        m = m2;
        idx = i2;
    } else if (m2 == m) {
        s += s2;                      // includes both -inf (s2==0) and exact-tie cases
        if (i2 < idx) idx = i2;       // first-index tie-break, matches jnp.argmax
    } else {
        s += s2 * expf(m2 - m);       // m2 - m == -inf -> 0 when other side empty
    }
}

// One block per row (row = b*4 + j). Computes argmax (global index) and NLL.
__global__ __launch_bounds__(256) void row_kernel(const float* __restrict__ yp,
                                                  const int* __restrict__ yt,
                                                  float* __restrict__ ws_nll,
                                                  int* __restrict__ ws_arg) {
    const int row = blockIdx.x;         // b*4 + j
    const int j = row & 3;
    const int tid = threadIdx.x;
    const int SIZES[4] = {100, 400, 2000, 8000};
    const int OFFS[4]  = {0, 100, 500, 2500};
    const int n = SIZES[j];
    const float* rowp = yp + (size_t)row * C_DIM;

    float m = -INFINITY, s = 0.0f;
    int idx = 0x7fffffff;
    for (int c = tid; c < n; c += 256) {
        float v = rowp[c];
        if (v > m) {                    // strict >: keeps earliest index within the stride
            s = s * expf(m - v) + 1.0f; // first iter: m=-inf -> expf(-inf)=0
            m = v;
            idx = c;
        } else {
            s += expf(v - m);
        }
    }

    // wave (64-lane) reduce
    for (int off = 32; off; off >>= 1) {
        float m2 = __shfl_down(m, off, 64);
        float s2 = __shfl_down(s, off, 64);
        int   i2 = __shfl_down(idx, off, 64);
        merge_softmax_argmax(m, s, idx, m2, s2, i2);
    }

    // cross-wave merge via LDS (4 waves)
    __shared__ float sm[4], ss[4];
    __shared__ int si[4];
    const int wave = tid >> 6;
    if ((tid & 63) == 0) { sm[wave] = m; ss[wave] = s; si[wave] = idx; }
    __syncthreads();
    if (tid == 0) {
        for (int w = 1; w < 4; ++w) {
            merge_softmax_argmax(m, s, idx, sm[w], ss[w], si[w]);
        }
        const int t = yt[row];                      // target index, in [0, n)
        const float lse = m + logf(s);              // logsumexp over valid prefix
        ws_nll[row] = -(rowp[t] - lse);             // NLL
        ws_arg[row] = idx + OFFS[j];                // global hierarchy index
    }
}

// Single block: per-sample combine (NLL mean + H consistency), then block reduce.
__global__ __launch_bounds__(256) void combine_kernel(const float* __restrict__ H,
                                                      const float* __restrict__ ws_nll,
                                                      const int* __restrict__ ws_arg,
                                                      float* __restrict__ out) {
    const int b = threadIdx.x;          // one thread per sample, B = 256 = blockDim
    const float W1 = 0.25f, W2 = 0.15f, W3 = 0.10f;
    const float E = 2.718281828459045f; // rounds to float32 np.e = 2.7182817f

    const int g0 = ws_arg[b * 4 + 0];
    const int g1 = ws_arg[b * 4 + 1];
    const int g2 = ws_arg[b * 4 + 2];
    const int g3 = ws_arg[b * 4 + 3];

    float p = 0.0f;
    p += W1 * (ws_nll[b * 4 + 1] * (1.0f / 256.0f));
    p += W2 * (ws_nll[b * 4 + 2] * (1.0f / 256.0f));
    p += W3 * (ws_nll[b * 4 + 3] * (1.0f / 256.0f));
    p += W1 * E * ((H[(size_t)g0 * N_TOTAL + g1] == 1.0f) ? 1.0f : 0.0f);
    p += W2 * E * ((H[(size_t)g1 * N_TOTAL + g2] == 1.0f) ? 1.0f : 0.0f);
    p += W3 * E * ((H[(size_t)g2 * N_TOTAL + g3] == 1.0f) ? 1.0f : 0.0f);

    for (int off = 32; off; off >>= 1) p += __shfl_down(p, off, 64);
    __shared__ float red[4];
    if ((b & 63) == 0) red[b >> 6] = p;
    __syncthreads();
    if (b == 0) out[0] = red[0] + red[1] + red[2] + red[3];
}

extern "C" void kernel_launch(void* const* d_in, const int* in_sizes, int n_in,
                              void* d_out, int out_size, void* d_ws, size_t ws_size,
                              hipStream_t stream) {
    const float* yp = (const float*)d_in[0];   // y_pred (256, 4, 8000) f32
    const int*   yt = (const int*)d_in[1];     // y_true (256, 4) i32
    const float* H  = (const float*)d_in[2];   // H (10500, 10500) f32

    float* ws_nll = (float*)d_ws;                                   // 1024 floats
    int*   ws_arg = (int*)((char*)d_ws + 1024 * sizeof(float));     // 1024 ints

    row_kernel<<<B_DIM * 4, 256, 0, stream>>>(yp, yt, ws_nll, ws_arg);
    combine_kernel<<<1, 256, 0, stream>>>(H, ws_nll, ws_arg, (float*)d_out);
}